// Round 1
// baseline (84.209 us; speedup 1.0000x reference)
//
#include <hip/hip_runtime.h>
#include <hip/hip_bf16.h>

#define BATCH 16384
#define FDIM  256
#define EDIM  128
#define KN    32
#define BM    32    // batch rows per block

typedef __bf16 bf16x8 __attribute__((ext_vector_type(8)));
typedef float  f32x4  __attribute__((ext_vector_type(4)));

__device__ __forceinline__ unsigned short f2bf(float x) {
    return __builtin_bit_cast(unsigned short, (__bf16)x);
}

// Fused GraphSAGE layer:
//   cat[b] = [ features[nodes[b]] , mean_k features[neigh[b][k]] ]   (bf16, LDS)
//   out[b] = relu(cat[b] @ W)                                        (bf16 MFMA, fp32 acc)
__global__ __launch_bounds__(256, 2)
void sage_fused(const int* __restrict__ nodes,
                const int* __restrict__ neigh,
                const float* __restrict__ feat,
                const float* __restrict__ weight,
                float* __restrict__ out)
{
    // cat tile: [BM][512] bf16, row stride 1024 B, XOR-swizzled by (row&7)<<4
    __shared__ __align__(16) char cat_raw[BM * 1024];
    // union region: phase0/1 = index staging; phase2 = Bt tile [c=128][k=128] bf16, swz by (c&7)<<4
    __shared__ __align__(16) char bt_raw[128 * 256];

    const int t    = threadIdx.x;
    const int lane = t & 63;
    const int w    = t >> 6;
    const int b0   = blockIdx.x * BM;

    // ---------------- phase 0: stage indices (into bt_raw region) ----------------
    int* ls_nei   = (int*)bt_raw;             // BM*KN = 1024 ints (4 KB)
    int* ls_nodes = (int*)(bt_raw + 4096);    // BM ints
    ((int4*)ls_nei)[t] = ((const int4*)(neigh + (size_t)b0 * KN))[t];  // 256 * int4 = 1024 ints
    if (t < BM) ls_nodes[t] = nodes[b0 + t];
    __syncthreads();

    // ---------------- phase 1: gather + mean-aggregate -> cat (bf16) ----------------
    // wave w owns rows w*8 .. w*8+7 ; lane l handles feature cols l*4..l*4+3
    for (int rr = 0; rr < 8; ++rr) {
        const int r   = w * 8 + rr;
        const int swz = (r & 7) << 4;
        const int nid = ls_nodes[r];

        // self half: cols [0,256)
        float4 s = ((const float4*)(feat + (size_t)nid * FDIM))[lane];
        {
            union { unsigned short u[4]; uint2 v; } p;
            p.u[0] = f2bf(s.x); p.u[1] = f2bf(s.y);
            p.u[2] = f2bf(s.z); p.u[3] = f2bf(s.w);
            *(uint2*)(cat_raw + ((r * 1024 + lane * 8) ^ swz)) = p.v;
        }

        // neighbor mean: cols [256,512)
        float ax0=0.f, ay0=0.f, az0=0.f, aw0=0.f;
        float ax1=0.f, ay1=0.f, az1=0.f, aw1=0.f;
        float ax2=0.f, ay2=0.f, az2=0.f, aw2=0.f;
        float ax3=0.f, ay3=0.f, az3=0.f, aw3=0.f;
        #pragma unroll
        for (int k = 0; k < KN; k += 4) {
            const int i0 = ls_nei[r * KN + k + 0];
            const int i1 = ls_nei[r * KN + k + 1];
            const int i2 = ls_nei[r * KN + k + 2];
            const int i3 = ls_nei[r * KN + k + 3];
            float4 v0 = ((const float4*)(feat + (size_t)i0 * FDIM))[lane];
            float4 v1 = ((const float4*)(feat + (size_t)i1 * FDIM))[lane];
            float4 v2 = ((const float4*)(feat + (size_t)i2 * FDIM))[lane];
            float4 v3 = ((const float4*)(feat + (size_t)i3 * FDIM))[lane];
            ax0 += v0.x; ay0 += v0.y; az0 += v0.z; aw0 += v0.w;
            ax1 += v1.x; ay1 += v1.y; az1 += v1.z; aw1 += v1.w;
            ax2 += v2.x; ay2 += v2.y; az2 += v2.z; aw2 += v2.w;
            ax3 += v3.x; ay3 += v3.y; az3 += v3.z; aw3 += v3.w;
        }
        const float inv = 1.0f / 32.0f;
        union { unsigned short u[4]; uint2 v; } p;
        p.u[0] = f2bf((ax0 + ax1 + ax2 + ax3) * inv);
        p.u[1] = f2bf((ay0 + ay1 + ay2 + ay3) * inv);
        p.u[2] = f2bf((az0 + az1 + az2 + az3) * inv);
        p.u[3] = f2bf((aw0 + aw1 + aw2 + aw3) * inv);
        *(uint2*)(cat_raw + ((r * 1024 + 512 + lane * 8) ^ swz)) = p.v;
    }
    __syncthreads();

    // ---------------- phase 2: GEMM cat[32][512] @ W[512][128] (bf16 MFMA) ----------------
    // 4 waves in 2x2: wave (wr,wc) computes rows r0..r0+15, cols c0..c0+63
    const int wr = w >> 1, wc = w & 1;
    const int r0 = wr * 16;
    const int c0 = wc * 64;
    const int q  = lane >> 4;     // quarter-wave: k-group selector
    const int p  = lane & 15;     // m (A) / n (B,D) index

    f32x4 acc[4] = {{0,0,0,0},{0,0,0,0},{0,0,0,0},{0,0,0,0}};

    for (int kt = 0; kt < 4; ++kt) {
        // stage Bt[c][kl] = bf16(W[kt*128+kl][c]), kl in [0,128), XOR-swizzled by c
        {
            const int c    = t & 127;
            const int kh   = (t >> 7) * 64;
            const int cswz = (c & 7) << 4;
            #pragma unroll
            for (int k8 = 0; k8 < 8; ++k8) {
                const int kl = kh + k8 * 8;
                union { unsigned short u[8]; uint4 v; } pk;
                #pragma unroll
                for (int j = 0; j < 8; ++j)
                    pk.u[j] = f2bf(weight[(size_t)(kt * 128 + kl + j) * EDIM + c]);
                *(uint4*)(bt_raw + ((c * 256 + kl * 2) ^ cswz)) = pk.v;
            }
        }
        __syncthreads();

        #pragma unroll
        for (int kk = 0; kk < 4; ++kk) {
            // A fragment: cat[r0+p][kt*128 + kk*32 + q*8 + (0..7)]
            const int row = r0 + p;
            const int kb  = (kt * 128 + kk * 32 + q * 8) * 2;
            bf16x8 a = *(const bf16x8*)(cat_raw + ((row * 1024 + kb) ^ ((row & 7) << 4)));
            const int klb = (kk * 32 + q * 8) * 2;
            #pragma unroll
            for (int n = 0; n < 4; ++n) {
                const int c = c0 + n * 16 + p;
                bf16x8 b = *(const bf16x8*)(bt_raw + ((c * 256 + klb) ^ ((c & 7) << 4)));
                acc[n] = __builtin_amdgcn_mfma_f32_16x16x32_bf16(a, b, acc[n], 0, 0, 0);
            }
        }
        __syncthreads();
    }

    // ---------------- epilogue: relu + store ----------------
    #pragma unroll
    for (int n = 0; n < 4; ++n) {
        #pragma unroll
        for (int j = 0; j < 4; ++j) {
            const int row = r0 + q * 4 + j;       // D: row = (lane>>4)*4 + reg
            const int col = c0 + n * 16 + p;      // D: col = lane&15
            float v = acc[n][j];
            out[(size_t)(b0 + row) * EDIM + col] = v > 0.f ? v : 0.f;
        }
    }
}

extern "C" void kernel_launch(void* const* d_in, const int* in_sizes, int n_in,
                              void* d_out, int out_size, void* d_ws, size_t ws_size,
                              hipStream_t stream) {
    const int*   nodes  = (const int*)d_in[0];
    const int*   neigh  = (const int*)d_in[1];
    const float* feat   = (const float*)d_in[2];
    const float* weight = (const float*)d_in[3];
    float*       out    = (float*)d_out;

    dim3 grid(BATCH / BM);   // 512 blocks, 2 per CU
    dim3 block(256);
    sage_fused<<<grid, block, 0, stream>>>(nodes, neigh, feat, weight, out);
}